// Round 9
// baseline (225.893 us; speedup 1.0000x reference)
//
#include <hip/hip_runtime.h>
#include <hip/hip_bf16.h>

#define DIM   1024
#define NHEAD 16
#define HD    64
#define SEQ   2048
#define BATCH 2
#define QKV3  3072

using short8 = __attribute__((ext_vector_type(8))) short;
using f32x4  = __attribute__((ext_vector_type(4))) float;

// fp32 -> bf16 (RNE) scalar
__device__ inline short f2bf(float f) {
    union { float f; unsigned u; } x; x.f = f;
    const unsigned r = (x.u + 0x7FFFu + ((x.u >> 16) & 1u)) >> 16;
    return (short)r;
}
// packed 2x fp32 -> bf16x2 (v_cvt_pk_bf16_f32)
__device__ inline unsigned pkbf(float a, float b) {
    union { __hip_bfloat162 h; unsigned u; } cv;
    cv.h = __float22bfloat162_rn(make_float2(a, b));
    return cv.u;
}

// async global->LDS DMA, 16 B per lane, LDS dest = wave-uniform base + lane*16.
__device__ __forceinline__ void g2l16(const void* gptr, void* ldsbase) {
    __builtin_amdgcn_global_load_lds(
        (const __attribute__((address_space(1))) unsigned int*)(unsigned long long)gptr,
        (__attribute__((address_space(3))) unsigned int*)(unsigned int)(unsigned long long)ldsbase,
        16, 0, 0);
}

// ======================================================================
// Convert x, W_kqv, W_out to bf16 (one pass).
// ======================================================================
__global__ __launch_bounds__(256)
void conv_bf16(const float* __restrict__ x, const float* __restrict__ wk,
               const float* __restrict__ wo,
               unsigned short* __restrict__ xb, unsigned short* __restrict__ wkb,
               unsigned short* __restrict__ wob)
{
    const int bid = blockIdx.x;
    const float* src; unsigned short* dst; size_t base;
    if (bid < 1024)      { src = x;  dst = xb;  base = (size_t)bid * 4096; }
    else if (bid < 1792) { src = wk; dst = wkb; base = (size_t)(bid - 1024) * 4096; }
    else                 { src = wo; dst = wob; base = (size_t)(bid - 1792) * 4096; }
    const size_t off = base + threadIdx.x * 16;
    const float4 f0 = *(const float4*)(src + off + 0);
    const float4 f1 = *(const float4*)(src + off + 4);
    const float4 f2 = *(const float4*)(src + off + 8);
    const float4 f3 = *(const float4*)(src + off + 12);
    uint4 o0, o1;
    o0.x = pkbf(f0.x, f0.y); o0.y = pkbf(f0.z, f0.w);
    o0.z = pkbf(f1.x, f1.y); o0.w = pkbf(f1.z, f1.w);
    o1.x = pkbf(f2.x, f2.y); o1.y = pkbf(f2.z, f2.w);
    o1.z = pkbf(f3.x, f3.y); o1.w = pkbf(f3.z, f3.w);
    *(uint4*)(dst + off + 0) = o0;
    *(uint4*)(dst + off + 8) = o1;
}

// ======================================================================
// QKV GEMM, bf16 MFMA.  R5 version: 3-buffer rotating DMA pipeline,
// counted vmcnt(4), one raw s_barrier/iter.  LDS 48 KB -> 3 blocks/CU.
// ======================================================================
__global__ __launch_bounds__(256)
void gemm_qkv(const unsigned short* __restrict__ A, const unsigned short* __restrict__ B,
              const float* __restrict__ bias,
              unsigned short* __restrict__ qbf, unsigned short* __restrict__ kbf,
              unsigned short* __restrict__ vtbf)
{
    constexpr int BK = 32, NIT = DIM / BK;
    const int K = DIM;
    __shared__ short As[3][128 * BK];   // 3 x 8 KB
    __shared__ short Bs[3][128 * BK];   // 3 x 8 KB

    const int tid  = threadIdx.x;
    const int lane = tid & 63;
    const int wave = tid >> 6;
    const int quad = lane >> 4;
    const int ln   = lane & 15;
    const int wm   = (wave & 1) * 64;
    const int wn   = (wave >> 1) * 64;

    const int bid = blockIdx.x;
    const int xcd = bid & 7;
    const int t   = bid >> 3;
    const int m0  = (xcd * 4 + (t & 3)) * 128;
    const int n0  = (t >> 2) * 128;

    int srow[2], sg[2];
#pragma unroll
    for (int i = 0; i < 2; ++i) {
        const int c  = wave * 128 + i * 64 + lane;
        srow[i] = c >> 2;
        sg[i]   = (c & 3) ^ ((srow[i] >> 1) & 3);
    }

    f32x4 acc[4][4];
#pragma unroll
    for (int i = 0; i < 4; ++i)
#pragma unroll
        for (int j = 0; j < 4; ++j) acc[i][j] = (f32x4){0.f, 0.f, 0.f, 0.f};

    // prologue: issue tiles 0 and 1 (8 DMA ops/thread outstanding)
#pragma unroll
    for (int t0 = 0; t0 < 2; ++t0) {
        const int kn = t0 * BK;
#pragma unroll
        for (int i = 0; i < 2; ++i) {
            const int cb = wave * 128 + i * 64;
            g2l16(A + (size_t)(m0 + srow[i]) * K + kn + sg[i] * 8, &As[t0][cb * 8]);
            g2l16(B + (size_t)(n0 + srow[i]) * K + kn + sg[i] * 8, &Bs[t0][cb * 8]);
        }
    }

    int bufc = 0;   // kt % 3
    int bufn = 2;   // (kt+2) % 3
    for (int kt = 0; kt < NIT; ++kt) {
        if (kt < NIT - 1) asm volatile("s_waitcnt vmcnt(4)" ::: "memory");
        else              asm volatile("s_waitcnt vmcnt(0)" ::: "memory");
        __builtin_amdgcn_s_barrier();
        __builtin_amdgcn_sched_barrier(0);

        short8 a[4], b[4];
#pragma unroll
        for (int i = 0; i < 4; ++i) {
            const int row = wm + i * 16 + ln;
            const int ch  = quad ^ ((row >> 1) & 3);
            a[i] = *(const short8*)&As[bufc][row * BK + ch * 8];
        }
#pragma unroll
        for (int j = 0; j < 4; ++j) {
            const int row = wn + j * 16 + ln;
            const int ch  = quad ^ ((row >> 1) & 3);
            b[j] = *(const short8*)&Bs[bufc][row * BK + ch * 8];
        }
        asm volatile("s_waitcnt lgkmcnt(0)" ::: "memory");
        __builtin_amdgcn_sched_barrier(0);

        if (kt + 2 < NIT) {
            const int kn = (kt + 2) * BK;
#pragma unroll
            for (int i = 0; i < 2; ++i) {
                const int cb = wave * 128 + i * 64;
                g2l16(A + (size_t)(m0 + srow[i]) * K + kn + sg[i] * 8, &As[bufn][cb * 8]);
                g2l16(B + (size_t)(n0 + srow[i]) * K + kn + sg[i] * 8, &Bs[bufn][cb * 8]);
            }
        }

#pragma unroll
        for (int i = 0; i < 4; ++i)
#pragma unroll
            for (int j = 0; j < 4; ++j)
                acc[i][j] = __builtin_amdgcn_mfma_f32_16x16x32_bf16(
                    a[i], b[j], acc[i][j], 0, 0, 0);

        bufc = (bufc == 2) ? 0 : bufc + 1;
        bufn = (bufn == 2) ? 0 : bufn + 1;
    }

#pragma unroll
    for (int j = 0; j < 4; ++j) {
        const int col = n0 + wn + j * 16 + ln;
        const int sel = col >> 10;
        const int c   = col & 1023;
        const int hh  = c >> 6;
        const int dd  = c & 63;
        const float bv = bias[col];
        if (sel < 2) {
            unsigned short* dst = (sel == 0) ? qbf : kbf;
            // 0.125 * log2(e): softmax becomes a bare exp2
            const float qs = (sel == 0) ? 0.18033688f : 1.0f;
#pragma unroll
            for (int i = 0; i < 4; ++i)
#pragma unroll
                for (int r2 = 0; r2 < 4; ++r2) {
                    const int row = m0 + wm + i * 16 + quad * 4 + r2;
                    const int bb = row >> 11, ss = row & 2047;
                    dst[((size_t)(bb * NHEAD + hh) * SEQ + ss) * HD + dd] =
                        (unsigned short)f2bf((acc[i][j][r2] + bv) * qs);
                }
        } else {
            const int row0 = m0 + wm + quad * 4;
            const int bb = row0 >> 11;
            const size_t vbase = ((size_t)(bb * NHEAD + hh) * HD + dd) * SEQ;
#pragma unroll
            for (int i = 0; i < 4; ++i) {
                const int ss0 = (row0 & 2047) + i * 16;
                uint2 pk;
                pk.x = pkbf(acc[i][j][0] + bv, acc[i][j][1] + bv);
                pk.y = pkbf(acc[i][j][2] + bv, acc[i][j][3] + bv);
                *(uint2*)&vtbf[vbase + ss0] = pk;
            }
        }
    }
}

// ======================================================================
// Flash attention, KV-split-in-block, KVBLK=64 (R5 structure).
// NEW this round: K fragments read DIRECTLY from global into registers
// (addresses have no wave index -> values bit-identical to the old LDS
// path; tile is XCD-L2-local so the 8x cross-wave redundancy is cache-
// absorbed).  Removes 8 of 16 ds_read_b128 per wave-iter (-50% LDS
// pipe), the lgkm hop before QK^T, and K's staging DMA.  Single K-reg
// buffer: next tile's loads issue right after QK^T consumes the regs;
// the per-iter __syncthreads (vmcnt(0) drain) guarantees arrival.
// V stays LDS-staged ping-pong (per-dj fragments differ).  LDS 32.5 KB.
// ======================================================================
__global__ __launch_bounds__(512, 4)
void attn_flash_mfma(const unsigned short* __restrict__ qbf,
                     const unsigned short* __restrict__ kbf,
                     const unsigned short* __restrict__ vtbf,
                     unsigned short* __restrict__ ctxbf)
{
    __shared__ short Vt[2][2][64 * 64];   // [buf][half]  32 KB
    __shared__ float Lbuf[128];

    const int tid  = threadIdx.x;
    const int lane = tid & 63;
    const int wave = tid >> 6;       // 0..7
    const int hf   = wave >> 2;      // KV half
    const int w4   = wave & 3;       // row-group within the q-tile
    const int quad = lane >> 4;
    const int ln   = lane & 15;

    const int bid = blockIdx.x;          // qt*32 + bh
    const int bh  = bid & 31;
    const int qt  = bid >> 5;
    const int q0  = qt * 128;
    const int b   = bh >> 4;
    const int h   = bh & 15;

    const size_t sbase = (size_t)bh * SEQ * HD;
    const size_t vbase = (size_t)bh * HD * SEQ;
    const int kv0 = hf * (SEQ / 2);

    const int tloc = tid & 255;
    int srw[2], scg[2];
#pragma unroll
    for (int it = 0; it < 2; ++it) {
        const int ch = tloc + it * 256;
        srw[it] = ch >> 3;
        scg[it] = (ch & 7) ^ (srw[it] & 7);
    }

    // Q fragments straight from global (one-time), 32 rows per wave
    short8 qf[2][2];
#pragma unroll
    for (int sm = 0; sm < 2; ++sm)
#pragma unroll
        for (int kc = 0; kc < 2; ++kc)
            qf[sm][kc] = *(const short8*)&qbf[sbase +
                (size_t)(q0 + w4 * 32 + sm * 16 + ln) * HD + kc * 32 + quad * 8];

    // K fragment registers for tile 0 (single-buffered)
    short8 kr[4][2];
#pragma unroll
    for (int j = 0; j < 4; ++j) {
        const unsigned short* kp = kbf + sbase + (size_t)(kv0 + j * 16 + ln) * HD + quad * 8;
        kr[j][0] = *(const short8*)(kp);
        kr[j][1] = *(const short8*)(kp + 32);
    }

    // prologue: DMA V tile 0 of this half -> buffer 0
#pragma unroll
    for (int it = 0; it < 2; ++it) {
        const int cb = tloc + it * 256;
        g2l16(vtbf + vbase + (size_t)srw[it] * SEQ + kv0 + scg[it] * 8,
              &Vt[0][hf][cb * 8]);
    }
    __syncthreads();

    f32x4 O[2][4];
#pragma unroll
    for (int sm = 0; sm < 2; ++sm)
#pragma unroll
        for (int dj = 0; dj < 4; ++dj) O[sm][dj] = (f32x4){0.f, 0.f, 0.f, 0.f};
    f32x4 lacc[2];
    lacc[0] = (f32x4){0.f, 0.f, 0.f, 0.f};
    lacc[1] = (f32x4){0.f, 0.f, 0.f, 0.f};

    short8 vone;
#pragma unroll
    for (int t = 0; t < 8; ++t) vone[t] = (short)0x3F80;

    constexpr int NIT = (SEQ / 2) / 64;   // 16
    for (int kt = 0; kt < NIT; ++kt) {
        const int p = kt & 1;
        if (kt + 1 < NIT) {
            const int k0n = kv0 + (kt + 1) * 64;
#pragma unroll
            for (int it = 0; it < 2; ++it) {
                const int cb = tloc + it * 256;
                g2l16(vtbf + vbase + (size_t)srw[it] * SEQ + k0n + scg[it] * 8,
                      &Vt[1 - p][hf][cb * 8]);
            }
        }

        // QK^T (swapped operands: A=K rows from REGISTERS, B=Q cols)
        f32x4 st[2][4];
        __builtin_amdgcn_s_setprio(1);
#pragma unroll
        for (int j = 0; j < 4; ++j) {
#pragma unroll
            for (int sm = 0; sm < 2; ++sm) {
                f32x4 tt = __builtin_amdgcn_mfma_f32_16x16x32_bf16(
                    kr[j][0], qf[sm][0], (f32x4){0.f, 0.f, 0.f, 0.f}, 0, 0, 0);
                st[sm][j] = __builtin_amdgcn_mfma_f32_16x16x32_bf16(
                    kr[j][1], qf[sm][1], tt, 0, 0, 0);
            }
        }
        __builtin_amdgcn_s_setprio(0);

        // issue next K-tile loads (regs consumed above; barrier drains)
        if (kt + 1 < NIT) {
            const int k0n = kv0 + (kt + 1) * 64;
#pragma unroll
            for (int j = 0; j < 4; ++j) {
                const unsigned short* kp = kbf + sbase +
                    (size_t)(k0n + j * 16 + ln) * HD + quad * 8;
                kr[j][0] = *(const short8*)(kp);
                kr[j][1] = *(const short8*)(kp + 32);
            }
        }

        // exp2 softmax + in-register transpose to PV A-fragments.
        short8 pf[2][2];
#pragma unroll
        for (int sm = 0; sm < 2; ++sm) {
            unsigned lo[4], hi[4];
#pragma unroll
            for (int j = 0; j < 4; ++j) {
                const float e0 = __builtin_amdgcn_exp2f(st[sm][j][0]);
                const float e1 = __builtin_amdgcn_exp2f(st[sm][j][1]);
                const float e2 = __builtin_amdgcn_exp2f(st[sm][j][2]);
                const float e3 = __builtin_amdgcn_exp2f(st[sm][j][3]);
                lo[j] = pkbf(e0, e1);
                hi[j] = pkbf(e2, e3);
            }
#pragma unroll
            for (int kc = 0; kc < 2; ++kc) {
                auto sa = __builtin_amdgcn_permlane32_swap(lo[2 * kc], lo[2 * kc + 1], false, false);
                auto sb = __builtin_amdgcn_permlane32_swap(hi[2 * kc], hi[2 * kc + 1], false, false);
                auto ua = __builtin_amdgcn_permlane16_swap(sa[0], sa[1], false, false);
                auto ub = __builtin_amdgcn_permlane16_swap(sb[0], sb[1], false, false);
                union { unsigned u[4]; short8 s; } cv;
                cv.u[0] = ua[0];   // k offsets {0,1}
                cv.u[1] = ub[0];   // k offsets {2,3}
                cv.u[2] = ua[1];   // k offsets {4,5}
                cv.u[3] = ub[1];   // k offsets {6,7}
                pf[sm][kc] = cv.s;
            }
        }

        // PV + l accumulation (l = P @ ones via MFMA)
        __builtin_amdgcn_s_setprio(1);
#pragma unroll
        for (int kc = 0; kc < 2; ++kc) {
            lacc[0] = __builtin_amdgcn_mfma_f32_16x16x32_bf16(pf[0][kc], vone, lacc[0], 0, 0, 0);
            lacc[1] = __builtin_amdgcn_mfma_f32_16x16x32_bf16(pf[1][kc], vone, lacc[1], 0, 0, 0);
#pragma unroll
            for (int dj = 0; dj < 4; ++dj) {
                const int row = dj * 16 + ln;
                const int cg  = (kc * 4 + quad) ^ (row & 7);
                const short8 vf = *(const short8*)&Vt[p][hf][row * 64 + cg * 8];
                O[0][dj] = __builtin_amdgcn_mfma_f32_16x16x32_bf16(pf[0][kc], vf, O[0][dj], 0, 0, 0);
                O[1][dj] = __builtin_amdgcn_mfma_f32_16x16x32_bf16(pf[1][kc], vf, O[1][dj], 0, 0, 0);
            }
        }
        __builtin_amdgcn_s_setprio(0);
        __syncthreads();   // drains V-DMA and K reg-loads for next iter
    }

    // ---- combine the two KV-halves: O = O_a + O_b, l = l_a + l_b ----
    // (exact for the no-max exp2 softmax).  Reuse Vt as 128x64 f32.
    float* Of = (float*)&Vt[0][0][0];
    if (hf == 0) {
#pragma unroll
        for (int sm = 0; sm < 2; ++sm) {
#pragma unroll
            for (int dj = 0; dj < 4; ++dj)
#pragma unroll
                for (int r2 = 0; r2 < 4; ++r2)
                    Of[(w4 * 32 + sm * 16 + quad * 4 + r2) * 64 + dj * 16 + ln] =
                        O[sm][dj][r2];
            if (ln == 0)
#pragma unroll
                for (int r2 = 0; r2 < 4; ++r2)
                    Lbuf[w4 * 32 + sm * 16 + quad * 4 + r2] = lacc[sm][r2];
        }
    }
    __syncthreads();
    if (hf == 1) {
#pragma unroll
        for (int sm = 0; sm < 2; ++sm)
#pragma unroll
            for (int r2 = 0; r2 < 4; ++r2) {
                const int rr = w4 * 32 + sm * 16 + quad * 4 + r2;
                const float inv = 1.0f / (lacc[sm][r2] + Lbuf[rr]);
                const int row = b * SEQ + q0 + rr;
#pragma unroll
                for (int dj = 0; dj < 4; ++dj) {
                    const float val = O[sm][dj][r2] + Of[rr * 64 + dj * 16 + ln];
                    ctxbf[(size_t)row * DIM + h * HD + dj * 16 + ln] =
                        (unsigned short)f2bf(val * inv);
                }
            }
    }
}

// ======================================================================
// Out-proj GEMM: R5 version (3-buffer counted-vmcnt DMA pipeline).
// ======================================================================
__global__ __launch_bounds__(256)
void gemm_out(const unsigned short* __restrict__ A, const unsigned short* __restrict__ B,
              const float* __restrict__ bias, float* __restrict__ C)
{
    constexpr int BK = 32, NIT = DIM / BK;
    const int K = DIM, N = DIM;
    __shared__ short As[3][128 * BK];   // 3 x 8 KB
    __shared__ short Bs[3][64 * BK];    // 3 x 4 KB

    const int tid  = threadIdx.x;
    const int lane = tid & 63;
    const int wave = tid >> 6;
    const int quad = lane >> 4;
    const int ln   = lane & 15;
    const int wm   = (wave & 1) * 64;
    const int wn   = (wave >> 1) * 32;

    const int bid = blockIdx.x;
    const int xcd = bid & 7;
    const int t   = bid >> 3;
    const int m0  = (xcd * 4 + (t & 3)) * 128;
    const int n0  = (t >> 2) * 64;

    int srow[2], sg[2];
#pragma unroll
    for (int i = 0; i < 2; ++i) {
        const int c  = wave * 128 + i * 64 + lane;
        srow[i] = c >> 2;
        sg[i]   = (c & 3) ^ ((srow[i] >> 1) & 3);
    }
    const int cB  = wave * 64 + lane;
    const int brow = cB >> 2;
    const int bg   = (cB & 3) ^ ((brow >> 1) & 3);

    f32x4 acc[4][2];
#pragma unroll
    for (int i = 0; i < 4; ++i)
#pragma unroll
        for (int j = 0; j < 2; ++j) acc[i][j] = (f32x4){0.f, 0.f, 0.f, 0.f};

    // prologue: issue tiles 0 and 1 (6 ops outstanding)
#pragma unroll
    for (int t0 = 0; t0 < 2; ++t0) {
        const int kn = t0 * BK;
#pragma unroll
        for (int i = 0; i < 2; ++i)
            g2l16(A + (size_t)(m0 + srow[i]) * K + kn + sg[i] * 8,
                  &As[t0][(wave * 128 + i * 64) * 8]);
        g2l16(B + (size_t)(n0 + brow) * K + kn + bg * 8, &Bs[t0][(wave * 64) * 8]);
    }

    int bufc = 0;
    int bufn = 2;
    for (int kt = 0; kt < NIT; ++kt) {
        if (kt < NIT - 1) asm volatile("s_waitcnt vmcnt(3)" ::: "memory");
        else              asm volatile("s_waitcnt vmcnt(0)" ::: "memory");
        __builtin_amdgcn_s_barrier();
        __builtin_amdgcn_sched_barrier(0);

        short8 a[4], b[2];
#pragma unroll
        for (int i = 0; i < 4; ++i) {
            const int row = wm + i * 16 + ln;
            const int ch  = quad ^ ((row >> 1) & 3);
            a[i] = *(const short8*)&As[bufc][row * BK + ch * 8];
        }
#pragma unroll
        for (int j = 0; j < 2; ++j) {
            const int row = wn + j * 16 + ln;
            const int ch  = quad ^ ((row >> 1) & 3);
            b[j] = *(const short8*)&Bs[bufc][row * BK + ch * 8];
        }
        asm volatile("s_waitcnt lgkmcnt(0)" ::: "memory");
        __builtin_amdgcn_sched_barrier(0);

        if (kt + 2 < NIT) {
            const int kn = (kt + 2) * BK;
#pragma unroll
            for (int i = 0; i < 2; ++i)
                g2l16(A + (size_t)(m0 + srow[i]) * K + kn + sg[i] * 8,
                      &As[bufn][(wave * 128 + i * 64) * 8]);
            g2l16(B + (size_t)(n0 + brow) * K + kn + bg * 8, &Bs[bufn][(wave * 64) * 8]);
        }

#pragma unroll
        for (int i = 0; i < 4; ++i)
#pragma unroll
            for (int j = 0; j < 2; ++j)
                acc[i][j] = __builtin_amdgcn_mfma_f32_16x16x32_bf16(
                    a[i], b[j], acc[i][j], 0, 0, 0);

        bufc = (bufc == 2) ? 0 : bufc + 1;
        bufn = (bufn == 2) ? 0 : bufn + 1;
    }

#pragma unroll
    for (int j = 0; j < 2; ++j) {
        const int col = n0 + wn + j * 16 + ln;
        const float bv = bias[col];
#pragma unroll
        for (int i = 0; i < 4; ++i)
#pragma unroll
            for (int r2 = 0; r2 < 4; ++r2) {
                const int row = m0 + wm + i * 16 + quad * 4 + r2;
                C[(size_t)row * N + col] = acc[i][j][r2] + bv;
            }
    }
}

extern "C" void kernel_launch(void* const* d_in, const int* in_sizes, int n_in,
                              void* d_out, int out_size, void* d_ws, size_t ws_size,
                              hipStream_t stream)
{
    const float* x     = (const float*)d_in[0];
    const float* W_kqv = (const float*)d_in[1];
    const float* b_kqv = (const float*)d_in[2];
    const float* W_out = (const float*)d_in[3];
    const float* b_out = (const float*)d_in[4];
    float* out = (float*)d_out;

    char* w = (char*)d_ws;
    unsigned short* qbf   = (unsigned short*)w;  w += (size_t)BATCH * NHEAD * SEQ * HD * 2;
    unsigned short* kbf   = (unsigned short*)w;  w += (size_t)BATCH * NHEAD * SEQ * HD * 2;
    unsigned short* vtbf  = (unsigned short*)w;  w += (size_t)BATCH * NHEAD * HD * SEQ * 2;
    unsigned short* ctxbf = (unsigned short*)w;  w += (size_t)BATCH * SEQ * DIM * 2;
    unsigned short* xb    = (unsigned short*)w;  w += (size_t)BATCH * SEQ * DIM * 2;
    unsigned short* wkb   = (unsigned short*)w;  w += (size_t)QKV3 * DIM * 2;
    unsigned short* wob   = (unsigned short*)w;

    dim3 blk(256);

    conv_bf16<<<dim3(2048), blk, 0, stream>>>(x, W_kqv, W_out, xb, wkb, wob);

    gemm_qkv<<<dim3(768), blk, 0, stream>>>(xb, wkb, b_kqv, qbf, kbf, vtbf);

    attn_flash_mfma<<<dim3(512), dim3(512), 0, stream>>>(qbf, kbf, vtbf, ctxbf);

    gemm_out<<<dim3(512), blk, 0, stream>>>(ctxbf, wob, b_out, out);
}

// Round 10
// 209.169 us; speedup vs baseline: 1.0800x; 1.0800x over previous
//
#include <hip/hip_runtime.h>
#include <hip/hip_bf16.h>

#define DIM   1024
#define NHEAD 16
#define HD    64
#define SEQ   2048
#define BATCH 2
#define QKV3  3072

using short8 = __attribute__((ext_vector_type(8))) short;
using f32x4  = __attribute__((ext_vector_type(4))) float;

// fp32 -> bf16 (RNE) scalar
__device__ inline short f2bf(float f) {
    union { float f; unsigned u; } x; x.f = f;
    const unsigned r = (x.u + 0x7FFFu + ((x.u >> 16) & 1u)) >> 16;
    return (short)r;
}
// packed 2x fp32 -> bf16x2 (v_cvt_pk_bf16_f32)
__device__ inline unsigned pkbf(float a, float b) {
    union { __hip_bfloat162 h; unsigned u; } cv;
    cv.h = __float22bfloat162_rn(make_float2(a, b));
    return cv.u;
}

// async global->LDS DMA, 16 B per lane, LDS dest = wave-uniform base + lane*16.
__device__ __forceinline__ void g2l16(const void* gptr, void* ldsbase) {
    __builtin_amdgcn_global_load_lds(
        (const __attribute__((address_space(1))) unsigned int*)(unsigned long long)gptr,
        (__attribute__((address_space(3))) unsigned int*)(unsigned int)(unsigned long long)ldsbase,
        16, 0, 0);
}

// ======================================================================
// Convert x, W_kqv, W_out to bf16 (one pass).
// ======================================================================
__global__ __launch_bounds__(256)
void conv_bf16(const float* __restrict__ x, const float* __restrict__ wk,
               const float* __restrict__ wo,
               unsigned short* __restrict__ xb, unsigned short* __restrict__ wkb,
               unsigned short* __restrict__ wob)
{
    const int bid = blockIdx.x;
    const float* src; unsigned short* dst; size_t base;
    if (bid < 1024)      { src = x;  dst = xb;  base = (size_t)bid * 4096; }
    else if (bid < 1792) { src = wk; dst = wkb; base = (size_t)(bid - 1024) * 4096; }
    else                 { src = wo; dst = wob; base = (size_t)(bid - 1792) * 4096; }
    const size_t off = base + threadIdx.x * 16;
    const float4 f0 = *(const float4*)(src + off + 0);
    const float4 f1 = *(const float4*)(src + off + 4);
    const float4 f2 = *(const float4*)(src + off + 8);
    const float4 f3 = *(const float4*)(src + off + 12);
    uint4 o0, o1;
    o0.x = pkbf(f0.x, f0.y); o0.y = pkbf(f0.z, f0.w);
    o0.z = pkbf(f1.x, f1.y); o0.w = pkbf(f1.z, f1.w);
    o1.x = pkbf(f2.x, f2.y); o1.y = pkbf(f2.z, f2.w);
    o1.z = pkbf(f3.x, f3.y); o1.w = pkbf(f3.z, f3.w);
    *(uint4*)(dst + off + 0) = o0;
    *(uint4*)(dst + off + 8) = o1;
}

// ======================================================================
// QKV GEMM, bf16 MFMA.  R5 version: 3-buffer rotating DMA pipeline,
// counted vmcnt(4), one raw s_barrier/iter.  LDS 48 KB -> 3 blocks/CU.
// ======================================================================
__global__ __launch_bounds__(256)
void gemm_qkv(const unsigned short* __restrict__ A, const unsigned short* __restrict__ B,
              const float* __restrict__ bias,
              unsigned short* __restrict__ qbf, unsigned short* __restrict__ kbf,
              unsigned short* __restrict__ vtbf)
{
    constexpr int BK = 32, NIT = DIM / BK;
    const int K = DIM;
    __shared__ short As[3][128 * BK];   // 3 x 8 KB
    __shared__ short Bs[3][128 * BK];   // 3 x 8 KB

    const int tid  = threadIdx.x;
    const int lane = tid & 63;
    const int wave = tid >> 6;
    const int quad = lane >> 4;
    const int ln   = lane & 15;
    const int wm   = (wave & 1) * 64;
    const int wn   = (wave >> 1) * 64;

    const int bid = blockIdx.x;
    const int xcd = bid & 7;
    const int t   = bid >> 3;
    const int m0  = (xcd * 4 + (t & 3)) * 128;
    const int n0  = (t >> 2) * 128;

    int srow[2], sg[2];
#pragma unroll
    for (int i = 0; i < 2; ++i) {
        const int c  = wave * 128 + i * 64 + lane;
        srow[i] = c >> 2;
        sg[i]   = (c & 3) ^ ((srow[i] >> 1) & 3);
    }

    f32x4 acc[4][4];
#pragma unroll
    for (int i = 0; i < 4; ++i)
#pragma unroll
        for (int j = 0; j < 4; ++j) acc[i][j] = (f32x4){0.f, 0.f, 0.f, 0.f};

    // prologue: issue tiles 0 and 1 (8 DMA ops/thread outstanding)
#pragma unroll
    for (int t0 = 0; t0 < 2; ++t0) {
        const int kn = t0 * BK;
#pragma unroll
        for (int i = 0; i < 2; ++i) {
            const int cb = wave * 128 + i * 64;
            g2l16(A + (size_t)(m0 + srow[i]) * K + kn + sg[i] * 8, &As[t0][cb * 8]);
            g2l16(B + (size_t)(n0 + srow[i]) * K + kn + sg[i] * 8, &Bs[t0][cb * 8]);
        }
    }

    int bufc = 0;   // kt % 3
    int bufn = 2;   // (kt+2) % 3
    for (int kt = 0; kt < NIT; ++kt) {
        if (kt < NIT - 1) asm volatile("s_waitcnt vmcnt(4)" ::: "memory");
        else              asm volatile("s_waitcnt vmcnt(0)" ::: "memory");
        __builtin_amdgcn_s_barrier();
        __builtin_amdgcn_sched_barrier(0);

        short8 a[4], b[4];
#pragma unroll
        for (int i = 0; i < 4; ++i) {
            const int row = wm + i * 16 + ln;
            const int ch  = quad ^ ((row >> 1) & 3);
            a[i] = *(const short8*)&As[bufc][row * BK + ch * 8];
        }
#pragma unroll
        for (int j = 0; j < 4; ++j) {
            const int row = wn + j * 16 + ln;
            const int ch  = quad ^ ((row >> 1) & 3);
            b[j] = *(const short8*)&Bs[bufc][row * BK + ch * 8];
        }
        asm volatile("s_waitcnt lgkmcnt(0)" ::: "memory");
        __builtin_amdgcn_sched_barrier(0);

        if (kt + 2 < NIT) {
            const int kn = (kt + 2) * BK;
#pragma unroll
            for (int i = 0; i < 2; ++i) {
                const int cb = wave * 128 + i * 64;
                g2l16(A + (size_t)(m0 + srow[i]) * K + kn + sg[i] * 8, &As[bufn][cb * 8]);
                g2l16(B + (size_t)(n0 + srow[i]) * K + kn + sg[i] * 8, &Bs[bufn][cb * 8]);
            }
        }

#pragma unroll
        for (int i = 0; i < 4; ++i)
#pragma unroll
            for (int j = 0; j < 4; ++j)
                acc[i][j] = __builtin_amdgcn_mfma_f32_16x16x32_bf16(
                    a[i], b[j], acc[i][j], 0, 0, 0);

        bufc = (bufc == 2) ? 0 : bufc + 1;
        bufn = (bufn == 2) ? 0 : bufn + 1;
    }

#pragma unroll
    for (int j = 0; j < 4; ++j) {
        const int col = n0 + wn + j * 16 + ln;
        const int sel = col >> 10;
        const int c   = col & 1023;
        const int hh  = c >> 6;
        const int dd  = c & 63;
        const float bv = bias[col];
        if (sel < 2) {
            unsigned short* dst = (sel == 0) ? qbf : kbf;
            // 0.125 * log2(e): softmax becomes a bare exp2
            const float qs = (sel == 0) ? 0.18033688f : 1.0f;
#pragma unroll
            for (int i = 0; i < 4; ++i)
#pragma unroll
                for (int r2 = 0; r2 < 4; ++r2) {
                    const int row = m0 + wm + i * 16 + quad * 4 + r2;
                    const int bb = row >> 11, ss = row & 2047;
                    dst[((size_t)(bb * NHEAD + hh) * SEQ + ss) * HD + dd] =
                        (unsigned short)f2bf((acc[i][j][r2] + bv) * qs);
                }
        } else {
            const int row0 = m0 + wm + quad * 4;
            const int bb = row0 >> 11;
            const size_t vbase = ((size_t)(bb * NHEAD + hh) * HD + dd) * SEQ;
#pragma unroll
            for (int i = 0; i < 4; ++i) {
                const int ss0 = (row0 & 2047) + i * 16;
                uint2 pk;
                pk.x = pkbf(acc[i][j][0] + bv, acc[i][j][1] + bv);
                pk.y = pkbf(acc[i][j][2] + bv, acc[i][j][3] + bv);
                *(uint2*)&vtbf[vbase + ss0] = pk;
            }
        }
    }
}

// ======================================================================
// Flash attention, KV-split-in-block, KVBLK=64, K-DIRECT-TO-REGISTER.
// Identical to R9's kernel (correctness-verified there, absmax 4.9e-4)
// EXCEPT __launch_bounds__(512) -- R9's (512,4) min-waves arg capped
// the allocator at 64 VGPR and spilled the 32-reg K buffer to scratch
// (WRITE_SIZE 8.2->25.6 MB, 2.2x slowdown).  Natural allocation
// (~100-120 VGPR <= 128) keeps 4 waves/SIMD, 2 blocks/CU, no spill.
// K fragments: wave-redundant addresses -> L1/L2 hits; removes 8/16
// ds_read_b128 per wave-iter + the lgkm hop before QK^T.  V stays
// LDS-staged ping-pong.  LDS 32.5 KB.
// ======================================================================
__global__ __launch_bounds__(512)
void attn_flash_mfma(const unsigned short* __restrict__ qbf,
                     const unsigned short* __restrict__ kbf,
                     const unsigned short* __restrict__ vtbf,
                     unsigned short* __restrict__ ctxbf)
{
    __shared__ short Vt[2][2][64 * 64];   // [buf][half]  32 KB
    __shared__ float Lbuf[128];

    const int tid  = threadIdx.x;
    const int lane = tid & 63;
    const int wave = tid >> 6;       // 0..7
    const int hf   = wave >> 2;      // KV half
    const int w4   = wave & 3;       // row-group within the q-tile
    const int quad = lane >> 4;
    const int ln   = lane & 15;

    const int bid = blockIdx.x;          // qt*32 + bh
    const int bh  = bid & 31;
    const int qt  = bid >> 5;
    const int q0  = qt * 128;
    const int b   = bh >> 4;
    const int h   = bh & 15;

    const size_t sbase = (size_t)bh * SEQ * HD;
    const size_t vbase = (size_t)bh * HD * SEQ;
    const int kv0 = hf * (SEQ / 2);

    const int tloc = tid & 255;
    int srw[2], scg[2];
#pragma unroll
    for (int it = 0; it < 2; ++it) {
        const int ch = tloc + it * 256;
        srw[it] = ch >> 3;
        scg[it] = (ch & 7) ^ (srw[it] & 7);
    }

    // Q fragments straight from global (one-time), 32 rows per wave
    short8 qf[2][2];
#pragma unroll
    for (int sm = 0; sm < 2; ++sm)
#pragma unroll
        for (int kc = 0; kc < 2; ++kc)
            qf[sm][kc] = *(const short8*)&qbf[sbase +
                (size_t)(q0 + w4 * 32 + sm * 16 + ln) * HD + kc * 32 + quad * 8];

    // K fragment registers for tile 0 (single-buffered)
    short8 kr[4][2];
#pragma unroll
    for (int j = 0; j < 4; ++j) {
        const unsigned short* kp = kbf + sbase + (size_t)(kv0 + j * 16 + ln) * HD + quad * 8;
        kr[j][0] = *(const short8*)(kp);
        kr[j][1] = *(const short8*)(kp + 32);
    }

    // prologue: DMA V tile 0 of this half -> buffer 0
#pragma unroll
    for (int it = 0; it < 2; ++it) {
        const int cb = tloc + it * 256;
        g2l16(vtbf + vbase + (size_t)srw[it] * SEQ + kv0 + scg[it] * 8,
              &Vt[0][hf][cb * 8]);
    }
    __syncthreads();

    f32x4 O[2][4];
#pragma unroll
    for (int sm = 0; sm < 2; ++sm)
#pragma unroll
        for (int dj = 0; dj < 4; ++dj) O[sm][dj] = (f32x4){0.f, 0.f, 0.f, 0.f};
    f32x4 lacc[2];
    lacc[0] = (f32x4){0.f, 0.f, 0.f, 0.f};
    lacc[1] = (f32x4){0.f, 0.f, 0.f, 0.f};

    short8 vone;
#pragma unroll
    for (int t = 0; t < 8; ++t) vone[t] = (short)0x3F80;

    constexpr int NIT = (SEQ / 2) / 64;   // 16
    for (int kt = 0; kt < NIT; ++kt) {
        const int p = kt & 1;
        if (kt + 1 < NIT) {
            const int k0n = kv0 + (kt + 1) * 64;
#pragma unroll
            for (int it = 0; it < 2; ++it) {
                const int cb = tloc + it * 256;
                g2l16(vtbf + vbase + (size_t)srw[it] * SEQ + k0n + scg[it] * 8,
                      &Vt[1 - p][hf][cb * 8]);
            }
        }

        // QK^T (swapped operands: A=K rows from REGISTERS, B=Q cols)
        f32x4 st[2][4];
        __builtin_amdgcn_s_setprio(1);
#pragma unroll
        for (int j = 0; j < 4; ++j) {
#pragma unroll
            for (int sm = 0; sm < 2; ++sm) {
                f32x4 tt = __builtin_amdgcn_mfma_f32_16x16x32_bf16(
                    kr[j][0], qf[sm][0], (f32x4){0.f, 0.f, 0.f, 0.f}, 0, 0, 0);
                st[sm][j] = __builtin_amdgcn_mfma_f32_16x16x32_bf16(
                    kr[j][1], qf[sm][1], tt, 0, 0, 0);
            }
        }
        __builtin_amdgcn_s_setprio(0);

        // issue next K-tile loads (regs consumed above; barrier drains)
        if (kt + 1 < NIT) {
            const int k0n = kv0 + (kt + 1) * 64;
#pragma unroll
            for (int j = 0; j < 4; ++j) {
                const unsigned short* kp = kbf + sbase +
                    (size_t)(k0n + j * 16 + ln) * HD + quad * 8;
                kr[j][0] = *(const short8*)(kp);
                kr[j][1] = *(const short8*)(kp + 32);
            }
        }

        // exp2 softmax + in-register transpose to PV A-fragments.
        short8 pf[2][2];
#pragma unroll
        for (int sm = 0; sm < 2; ++sm) {
            unsigned lo[4], hi[4];
#pragma unroll
            for (int j = 0; j < 4; ++j) {
                const float e0 = __builtin_amdgcn_exp2f(st[sm][j][0]);
                const float e1 = __builtin_amdgcn_exp2f(st[sm][j][1]);
                const float e2 = __builtin_amdgcn_exp2f(st[sm][j][2]);
                const float e3 = __builtin_amdgcn_exp2f(st[sm][j][3]);
                lo[j] = pkbf(e0, e1);
                hi[j] = pkbf(e2, e3);
            }
#pragma unroll
            for (int kc = 0; kc < 2; ++kc) {
                auto sa = __builtin_amdgcn_permlane32_swap(lo[2 * kc], lo[2 * kc + 1], false, false);
                auto sb = __builtin_amdgcn_permlane32_swap(hi[2 * kc], hi[2 * kc + 1], false, false);
                auto ua = __builtin_amdgcn_permlane16_swap(sa[0], sa[1], false, false);
                auto ub = __builtin_amdgcn_permlane16_swap(sb[0], sb[1], false, false);
                union { unsigned u[4]; short8 s; } cv;
                cv.u[0] = ua[0];   // k offsets {0,1}
                cv.u[1] = ub[0];   // k offsets {2,3}
                cv.u[2] = ua[1];   // k offsets {4,5}
                cv.u[3] = ub[1];   // k offsets {6,7}
                pf[sm][kc] = cv.s;
            }
        }

        // PV + l accumulation (l = P @ ones via MFMA)
        __builtin_amdgcn_s_setprio(1);
#pragma unroll
        for (int kc = 0; kc < 2; ++kc) {
            lacc[0] = __builtin_amdgcn_mfma_f32_16x16x32_bf16(pf[0][kc], vone, lacc[0], 0, 0, 0);
            lacc[1] = __builtin_amdgcn_mfma_f32_16x16x32_bf16(pf[1][kc], vone, lacc[1], 0, 0, 0);
#pragma unroll
            for (int dj = 0; dj < 4; ++dj) {
                const int row = dj * 16 + ln;
                const int cg  = (kc * 4 + quad) ^ (row & 7);
                const short8 vf = *(const short8*)&Vt[p][hf][row * 64 + cg * 8];
                O[0][dj] = __builtin_amdgcn_mfma_f32_16x16x32_bf16(pf[0][kc], vf, O[0][dj], 0, 0, 0);
                O[1][dj] = __builtin_amdgcn_mfma_f32_16x16x32_bf16(pf[1][kc], vf, O[1][dj], 0, 0, 0);
            }
        }
        __builtin_amdgcn_s_setprio(0);
        __syncthreads();   // drains V-DMA and K reg-loads for next iter
    }

    // ---- combine the two KV-halves: O = O_a + O_b, l = l_a + l_b ----
    // (exact for the no-max exp2 softmax).  Reuse Vt as 128x64 f32.
    float* Of = (float*)&Vt[0][0][0];
    if (hf == 0) {
#pragma unroll
        for (int sm = 0; sm < 2; ++sm) {
#pragma unroll
            for (int dj = 0; dj < 4; ++dj)
#pragma unroll
                for (int r2 = 0; r2 < 4; ++r2)
                    Of[(w4 * 32 + sm * 16 + quad * 4 + r2) * 64 + dj * 16 + ln] =
                        O[sm][dj][r2];
            if (ln == 0)
#pragma unroll
                for (int r2 = 0; r2 < 4; ++r2)
                    Lbuf[w4 * 32 + sm * 16 + quad * 4 + r2] = lacc[sm][r2];
        }
    }
    __syncthreads();
    if (hf == 1) {
#pragma unroll
        for (int sm = 0; sm < 2; ++sm)
#pragma unroll
            for (int r2 = 0; r2 < 4; ++r2) {
                const int rr = w4 * 32 + sm * 16 + quad * 4 + r2;
                const float inv = 1.0f / (lacc[sm][r2] + Lbuf[rr]);
                const int row = b * SEQ + q0 + rr;
#pragma unroll
                for (int dj = 0; dj < 4; ++dj) {
                    const float val = O[sm][dj][r2] + Of[rr * 64 + dj * 16 + ln];
                    ctxbf[(size_t)row * DIM + h * HD + dj * 16 + ln] =
                        (unsigned short)f2bf(val * inv);
                }
            }
    }
}

// ======================================================================
// Out-proj GEMM: R5 version (3-buffer counted-vmcnt DMA pipeline).
// ======================================================================
__global__ __launch_bounds__(256)
void gemm_out(const unsigned short* __restrict__ A, const unsigned short* __restrict__ B,
              const float* __restrict__ bias, float* __restrict__ C)
{
    constexpr int BK = 32, NIT = DIM / BK;
    const int K = DIM, N = DIM;
    __shared__ short As[3][128 * BK];   // 3 x 8 KB
    __shared__ short Bs[3][64 * BK];    // 3 x 4 KB

    const int tid  = threadIdx.x;
    const int lane = tid & 63;
    const int wave = tid >> 6;
    const int quad = lane >> 4;
    const int ln   = lane & 15;
    const int wm   = (wave & 1) * 64;
    const int wn   = (wave >> 1) * 32;

    const int bid = blockIdx.x;
    const int xcd = bid & 7;
    const int t   = bid >> 3;
    const int m0  = (xcd * 4 + (t & 3)) * 128;
    const int n0  = (t >> 2) * 64;

    int srow[2], sg[2];
#pragma unroll
    for (int i = 0; i < 2; ++i) {
        const int c  = wave * 128 + i * 64 + lane;
        srow[i] = c >> 2;
        sg[i]   = (c & 3) ^ ((srow[i] >> 1) & 3);
    }
    const int cB  = wave * 64 + lane;
    const int brow = cB >> 2;
    const int bg   = (cB & 3) ^ ((brow >> 1) & 3);

    f32x4 acc[4][2];
#pragma unroll
    for (int i = 0; i < 4; ++i)
#pragma unroll
        for (int j = 0; j < 2; ++j) acc[i][j] = (f32x4){0.f, 0.f, 0.f, 0.f};

    // prologue: issue tiles 0 and 1 (6 ops outstanding)
#pragma unroll
    for (int t0 = 0; t0 < 2; ++t0) {
        const int kn = t0 * BK;
#pragma unroll
        for (int i = 0; i < 2; ++i)
            g2l16(A + (size_t)(m0 + srow[i]) * K + kn + sg[i] * 8,
                  &As[t0][(wave * 128 + i * 64) * 8]);
        g2l16(B + (size_t)(n0 + brow) * K + kn + bg * 8, &Bs[t0][(wave * 64) * 8]);
    }

    int bufc = 0;
    int bufn = 2;
    for (int kt = 0; kt < NIT; ++kt) {
        if (kt < NIT - 1) asm volatile("s_waitcnt vmcnt(3)" ::: "memory");
        else              asm volatile("s_waitcnt vmcnt(0)" ::: "memory");
        __builtin_amdgcn_s_barrier();
        __builtin_amdgcn_sched_barrier(0);

        short8 a[4], b[2];
#pragma unroll
        for (int i = 0; i < 4; ++i) {
            const int row = wm + i * 16 + ln;
            const int ch  = quad ^ ((row >> 1) & 3);
            a[i] = *(const short8*)&As[bufc][row * BK + ch * 8];
        }
#pragma unroll
        for (int j = 0; j < 2; ++j) {
            const int row = wn + j * 16 + ln;
            const int ch  = quad ^ ((row >> 1) & 3);
            b[j] = *(const short8*)&Bs[bufc][row * BK + ch * 8];
        }
        asm volatile("s_waitcnt lgkmcnt(0)" ::: "memory");
        __builtin_amdgcn_sched_barrier(0);

        if (kt + 2 < NIT) {
            const int kn = (kt + 2) * BK;
#pragma unroll
            for (int i = 0; i < 2; ++i)
                g2l16(A + (size_t)(m0 + srow[i]) * K + kn + sg[i] * 8,
                      &As[bufn][(wave * 128 + i * 64) * 8]);
            g2l16(B + (size_t)(n0 + brow) * K + kn + bg * 8, &Bs[bufn][(wave * 64) * 8]);
        }

#pragma unroll
        for (int i = 0; i < 4; ++i)
#pragma unroll
            for (int j = 0; j < 2; ++j)
                acc[i][j] = __builtin_amdgcn_mfma_f32_16x16x32_bf16(
                    a[i], b[j], acc[i][j], 0, 0, 0);

        bufc = (bufc == 2) ? 0 : bufc + 1;
        bufn = (bufn == 2) ? 0 : bufn + 1;
    }

#pragma unroll
    for (int j = 0; j < 2; ++j) {
        const int col = n0 + wn + j * 16 + ln;
        const float bv = bias[col];
#pragma unroll
        for (int i = 0; i < 4; ++i)
#pragma unroll
            for (int r2 = 0; r2 < 4; ++r2) {
                const int row = m0 + wm + i * 16 + quad * 4 + r2;
                C[(size_t)row * N + col] = acc[i][j][r2] + bv;
            }
    }
}

extern "C" void kernel_launch(void* const* d_in, const int* in_sizes, int n_in,
                              void* d_out, int out_size, void* d_ws, size_t ws_size,
                              hipStream_t stream)
{
    const float* x     = (const float*)d_in[0];
    const float* W_kqv = (const float*)d_in[1];
    const float* b_kqv = (const float*)d_in[2];
    const float* W_out = (const float*)d_in[3];
    const float* b_out = (const float*)d_in[4];
    float* out = (float*)d_out;

    char* w = (char*)d_ws;
    unsigned short* qbf   = (unsigned short*)w;  w += (size_t)BATCH * NHEAD * SEQ * HD * 2;
    unsigned short* kbf   = (unsigned short*)w;  w += (size_t)BATCH * NHEAD * SEQ * HD * 2;
    unsigned short* vtbf  = (unsigned short*)w;  w += (size_t)BATCH * NHEAD * HD * SEQ * 2;
    unsigned short* ctxbf = (unsigned short*)w;  w += (size_t)BATCH * SEQ * DIM * 2;
    unsigned short* xb    = (unsigned short*)w;  w += (size_t)BATCH * SEQ * DIM * 2;
    unsigned short* wkb   = (unsigned short*)w;  w += (size_t)QKV3 * DIM * 2;
    unsigned short* wob   = (unsigned short*)w;

    dim3 blk(256);

    conv_bf16<<<dim3(2048), blk, 0, stream>>>(x, W_kqv, W_out, xb, wkb, wob);

    gemm_qkv<<<dim3(768), blk, 0, stream>>>(xb, wkb, b_kqv, qbf, kbf, vtbf);

    attn_flash_mfma<<<dim3(512), dim3(512), 0, stream>>>(qbf, kbf, vtbf, ctxbf);

    gemm_out<<<dim3(512), blk, 0, stream>>>(ctxbf, wob, b_out, out);
}

// Round 11
// 171.662 us; speedup vs baseline: 1.3159x; 1.2185x over previous
//
#include <hip/hip_runtime.h>
#include <hip/hip_bf16.h>

#define DIM   1024
#define NHEAD 16
#define HD    64
#define SEQ   2048
#define BATCH 2
#define QKV3  3072

using short8 = __attribute__((ext_vector_type(8))) short;
using f32x4  = __attribute__((ext_vector_type(4))) float;

// fp32 -> bf16 (RNE) scalar
__device__ inline short f2bf(float f) {
    union { float f; unsigned u; } x; x.f = f;
    const unsigned r = (x.u + 0x7FFFu + ((x.u >> 16) & 1u)) >> 16;
    return (short)r;
}
// packed 2x fp32 -> bf16x2 (v_cvt_pk_bf16_f32)
__device__ inline unsigned pkbf(float a, float b) {
    union { __hip_bfloat162 h; unsigned u; } cv;
    cv.h = __float22bfloat162_rn(make_float2(a, b));
    return cv.u;
}

// async global->LDS DMA, 16 B per lane, LDS dest = wave-uniform base + lane*16.
__device__ __forceinline__ void g2l16(const void* gptr, void* ldsbase) {
    __builtin_amdgcn_global_load_lds(
        (const __attribute__((address_space(1))) unsigned int*)(unsigned long long)gptr,
        (__attribute__((address_space(3))) unsigned int*)(unsigned int)(unsigned long long)ldsbase,
        16, 0, 0);
}

// ======================================================================
// Convert x, W_kqv, W_out to bf16 (one pass).
// ======================================================================
__global__ __launch_bounds__(256)
void conv_bf16(const float* __restrict__ x, const float* __restrict__ wk,
               const float* __restrict__ wo,
               unsigned short* __restrict__ xb, unsigned short* __restrict__ wkb,
               unsigned short* __restrict__ wob)
{
    const int bid = blockIdx.x;
    const float* src; unsigned short* dst; size_t base;
    if (bid < 1024)      { src = x;  dst = xb;  base = (size_t)bid * 4096; }
    else if (bid < 1792) { src = wk; dst = wkb; base = (size_t)(bid - 1024) * 4096; }
    else                 { src = wo; dst = wob; base = (size_t)(bid - 1792) * 4096; }
    const size_t off = base + threadIdx.x * 16;
    const float4 f0 = *(const float4*)(src + off + 0);
    const float4 f1 = *(const float4*)(src + off + 4);
    const float4 f2 = *(const float4*)(src + off + 8);
    const float4 f3 = *(const float4*)(src + off + 12);
    uint4 o0, o1;
    o0.x = pkbf(f0.x, f0.y); o0.y = pkbf(f0.z, f0.w);
    o0.z = pkbf(f1.x, f1.y); o0.w = pkbf(f1.z, f1.w);
    o1.x = pkbf(f2.x, f2.y); o1.y = pkbf(f2.z, f2.w);
    o1.z = pkbf(f3.x, f3.y); o1.w = pkbf(f3.z, f3.w);
    *(uint4*)(dst + off + 0) = o0;
    *(uint4*)(dst + off + 8) = o1;
}

// ======================================================================
// QKV GEMM, bf16 MFMA.  3-buffer rotating DMA pipeline, counted
// vmcnt(4), one raw s_barrier/iter.  LDS 48 KB -> 3 blocks/CU.
// ======================================================================
__global__ __launch_bounds__(256)
void gemm_qkv(const unsigned short* __restrict__ A, const unsigned short* __restrict__ B,
              const float* __restrict__ bias,
              unsigned short* __restrict__ qbf, unsigned short* __restrict__ kbf,
              unsigned short* __restrict__ vtbf)
{
    constexpr int BK = 32, NIT = DIM / BK;
    const int K = DIM;
    __shared__ short As[3][128 * BK];   // 3 x 8 KB
    __shared__ short Bs[3][128 * BK];   // 3 x 8 KB

    const int tid  = threadIdx.x;
    const int lane = tid & 63;
    const int wave = tid >> 6;
    const int quad = lane >> 4;
    const int ln   = lane & 15;
    const int wm   = (wave & 1) * 64;
    const int wn   = (wave >> 1) * 64;

    const int bid = blockIdx.x;
    const int xcd = bid & 7;
    const int t   = bid >> 3;
    const int m0  = (xcd * 4 + (t & 3)) * 128;
    const int n0  = (t >> 2) * 128;

    int srow[2], sg[2];
#pragma unroll
    for (int i = 0; i < 2; ++i) {
        const int c  = wave * 128 + i * 64 + lane;
        srow[i] = c >> 2;
        sg[i]   = (c & 3) ^ ((srow[i] >> 1) & 3);
    }

    f32x4 acc[4][4];
#pragma unroll
    for (int i = 0; i < 4; ++i)
#pragma unroll
        for (int j = 0; j < 4; ++j) acc[i][j] = (f32x4){0.f, 0.f, 0.f, 0.f};

    // prologue: issue tiles 0 and 1 (8 DMA ops/thread outstanding)
#pragma unroll
    for (int t0 = 0; t0 < 2; ++t0) {
        const int kn = t0 * BK;
#pragma unroll
        for (int i = 0; i < 2; ++i) {
            const int cb = wave * 128 + i * 64;
            g2l16(A + (size_t)(m0 + srow[i]) * K + kn + sg[i] * 8, &As[t0][cb * 8]);
            g2l16(B + (size_t)(n0 + srow[i]) * K + kn + sg[i] * 8, &Bs[t0][cb * 8]);
        }
    }

    int bufc = 0;   // kt % 3
    int bufn = 2;   // (kt+2) % 3
    for (int kt = 0; kt < NIT; ++kt) {
        if (kt < NIT - 1) asm volatile("s_waitcnt vmcnt(4)" ::: "memory");
        else              asm volatile("s_waitcnt vmcnt(0)" ::: "memory");
        __builtin_amdgcn_s_barrier();
        __builtin_amdgcn_sched_barrier(0);

        short8 a[4], b[4];
#pragma unroll
        for (int i = 0; i < 4; ++i) {
            const int row = wm + i * 16 + ln;
            const int ch  = quad ^ ((row >> 1) & 3);
            a[i] = *(const short8*)&As[bufc][row * BK + ch * 8];
        }
#pragma unroll
        for (int j = 0; j < 4; ++j) {
            const int row = wn + j * 16 + ln;
            const int ch  = quad ^ ((row >> 1) & 3);
            b[j] = *(const short8*)&Bs[bufc][row * BK + ch * 8];
        }
        asm volatile("s_waitcnt lgkmcnt(0)" ::: "memory");
        __builtin_amdgcn_sched_barrier(0);

        if (kt + 2 < NIT) {
            const int kn = (kt + 2) * BK;
#pragma unroll
            for (int i = 0; i < 2; ++i) {
                const int cb = wave * 128 + i * 64;
                g2l16(A + (size_t)(m0 + srow[i]) * K + kn + sg[i] * 8, &As[bufn][cb * 8]);
                g2l16(B + (size_t)(n0 + srow[i]) * K + kn + sg[i] * 8, &Bs[bufn][cb * 8]);
            }
        }

#pragma unroll
        for (int i = 0; i < 4; ++i)
#pragma unroll
            for (int j = 0; j < 4; ++j)
                acc[i][j] = __builtin_amdgcn_mfma_f32_16x16x32_bf16(
                    a[i], b[j], acc[i][j], 0, 0, 0);

        bufc = (bufc == 2) ? 0 : bufc + 1;
        bufn = (bufn == 2) ? 0 : bufn + 1;
    }

#pragma unroll
    for (int j = 0; j < 4; ++j) {
        const int col = n0 + wn + j * 16 + ln;
        const int sel = col >> 10;
        const int c   = col & 1023;
        const int hh  = c >> 6;
        const int dd  = c & 63;
        const float bv = bias[col];
        if (sel < 2) {
            unsigned short* dst = (sel == 0) ? qbf : kbf;
            // 0.125 * log2(e): softmax becomes a bare exp2
            const float qs = (sel == 0) ? 0.18033688f : 1.0f;
#pragma unroll
            for (int i = 0; i < 4; ++i)
#pragma unroll
                for (int r2 = 0; r2 < 4; ++r2) {
                    const int row = m0 + wm + i * 16 + quad * 4 + r2;
                    const int bb = row >> 11, ss = row & 2047;
                    dst[((size_t)(bb * NHEAD + hh) * SEQ + ss) * HD + dd] =
                        (unsigned short)f2bf((acc[i][j][r2] + bv) * qs);
                }
        } else {
            const int row0 = m0 + wm + quad * 4;
            const int bb = row0 >> 11;
            const size_t vbase = ((size_t)(bb * NHEAD + hh) * HD + dd) * SEQ;
#pragma unroll
            for (int i = 0; i < 4; ++i) {
                const int ss0 = (row0 & 2047) + i * 16;
                uint2 pk;
                pk.x = pkbf(acc[i][j][0] + bv, acc[i][j][1] + bv);
                pk.y = pkbf(acc[i][j][2] + bv, acc[i][j][3] + bv);
                *(uint2*)&vtbf[vbase + ss0] = pk;
            }
        }
    }
}

// ======================================================================
// Flash attention, KV-SPLIT-IN-BLOCK (verified-best R5 version).
// 512 threads / 8 waves, BQ=128: waves 0-3 keys [0,1024), waves 4-7
// keys [1024,2048); exact combine via O=O_a+O_b, l=l_a+l_b (no-max
// exp2 softmax).  2 blocks/CU, in-register P (cvt_pk + permlane
// transpose), ping-pong DMA K/V staging, 1 barrier/iter.
// ======================================================================
__global__ __launch_bounds__(512)
void attn_flash_mfma(const unsigned short* __restrict__ qbf,
                     const unsigned short* __restrict__ kbf,
                     const unsigned short* __restrict__ vtbf,
                     unsigned short* __restrict__ ctxbf)
{
    __shared__ short Ks[2][2][64 * 64];   // [buf][half][row*64+c]  32 KB
    __shared__ short Vt[2][2][64 * 64];   // 32 KB

    const int tid  = threadIdx.x;
    const int lane = tid & 63;
    const int wave = tid >> 6;       // 0..7
    const int hf   = wave >> 2;      // KV half
    const int w4   = wave & 3;       // row-group within the q-tile
    const int quad = lane >> 4;
    const int ln   = lane & 15;

    const int bid = blockIdx.x;          // qt*32 + bh
    const int bh  = bid & 31;
    const int qt  = bid >> 5;
    const int q0  = qt * 128;
    const int b   = bh >> 4;
    const int h   = bh & 15;

    const size_t sbase = (size_t)bh * SEQ * HD;
    const size_t vbase = (size_t)bh * HD * SEQ;
    const int kv0 = hf * (SEQ / 2);

    const int tloc = tid & 255;
    int srw[2], scg[2];
#pragma unroll
    for (int it = 0; it < 2; ++it) {
        const int ch = tloc + it * 256;
        srw[it] = ch >> 3;
        scg[it] = (ch & 7) ^ (srw[it] & 7);
    }

    // Q fragments straight from global (one-time), 32 rows per wave
    short8 qf[2][2];
#pragma unroll
    for (int sm = 0; sm < 2; ++sm)
#pragma unroll
        for (int kc = 0; kc < 2; ++kc)
            qf[sm][kc] = *(const short8*)&qbf[sbase +
                (size_t)(q0 + w4 * 32 + sm * 16 + ln) * HD + kc * 32 + quad * 8];

    // prologue: DMA K/V tile 0 of this half -> buffer 0
#pragma unroll
    for (int it = 0; it < 2; ++it) {
        const int cb = tloc + it * 256;
        g2l16(kbf + sbase + (size_t)(kv0 + srw[it]) * HD + scg[it] * 8,
              &Ks[0][hf][cb * 8]);
        g2l16(vtbf + vbase + (size_t)srw[it] * SEQ + kv0 + scg[it] * 8,
              &Vt[0][hf][cb * 8]);
    }
    __syncthreads();

    f32x4 O[2][4];
#pragma unroll
    for (int sm = 0; sm < 2; ++sm)
#pragma unroll
        for (int dj = 0; dj < 4; ++dj) O[sm][dj] = (f32x4){0.f, 0.f, 0.f, 0.f};
    f32x4 lacc[2];
    lacc[0] = (f32x4){0.f, 0.f, 0.f, 0.f};
    lacc[1] = (f32x4){0.f, 0.f, 0.f, 0.f};

    short8 vone;
#pragma unroll
    for (int t = 0; t < 8; ++t) vone[t] = (short)0x3F80;

    constexpr int NIT = (SEQ / 2) / 64;   // 16
    for (int kt = 0; kt < NIT; ++kt) {
        const int p = kt & 1;
        if (kt + 1 < NIT) {
            const int k0n = kv0 + (kt + 1) * 64;
#pragma unroll
            for (int it = 0; it < 2; ++it) {
                const int cb = tloc + it * 256;
                g2l16(kbf + sbase + (size_t)(k0n + srw[it]) * HD + scg[it] * 8,
                      &Ks[1 - p][hf][cb * 8]);
                g2l16(vtbf + vbase + (size_t)srw[it] * SEQ + k0n + scg[it] * 8,
                      &Vt[1 - p][hf][cb * 8]);
            }
        }

        // QK^T (swapped operands: A=K rows, B=Q cols)
        f32x4 st[2][4];
        __builtin_amdgcn_s_setprio(1);
#pragma unroll
        for (int j = 0; j < 4; ++j) {
            const int row = j * 16 + ln;
            const int c0 = quad ^ (row & 7);
            const int c1 = (4 + quad) ^ (row & 7);
            const short8 kf0 = *(const short8*)&Ks[p][hf][row * 64 + c0 * 8];
            const short8 kf1 = *(const short8*)&Ks[p][hf][row * 64 + c1 * 8];
#pragma unroll
            for (int sm = 0; sm < 2; ++sm) {
                f32x4 tt = __builtin_amdgcn_mfma_f32_16x16x32_bf16(
                    kf0, qf[sm][0], (f32x4){0.f, 0.f, 0.f, 0.f}, 0, 0, 0);
                st[sm][j] = __builtin_amdgcn_mfma_f32_16x16x32_bf16(
                    kf1, qf[sm][1], tt, 0, 0, 0);
            }
        }
        __builtin_amdgcn_s_setprio(0);

        // exp2 softmax + in-register transpose to PV A-fragments.
        short8 pf[2][2];
#pragma unroll
        for (int sm = 0; sm < 2; ++sm) {
            unsigned lo[4], hi[4];
#pragma unroll
            for (int j = 0; j < 4; ++j) {
                const float e0 = __builtin_amdgcn_exp2f(st[sm][j][0]);
                const float e1 = __builtin_amdgcn_exp2f(st[sm][j][1]);
                const float e2 = __builtin_amdgcn_exp2f(st[sm][j][2]);
                const float e3 = __builtin_amdgcn_exp2f(st[sm][j][3]);
                lo[j] = pkbf(e0, e1);
                hi[j] = pkbf(e2, e3);
            }
#pragma unroll
            for (int kc = 0; kc < 2; ++kc) {
                auto sa = __builtin_amdgcn_permlane32_swap(lo[2 * kc], lo[2 * kc + 1], false, false);
                auto sb = __builtin_amdgcn_permlane32_swap(hi[2 * kc], hi[2 * kc + 1], false, false);
                auto ua = __builtin_amdgcn_permlane16_swap(sa[0], sa[1], false, false);
                auto ub = __builtin_amdgcn_permlane16_swap(sb[0], sb[1], false, false);
                union { unsigned u[4]; short8 s; } cv;
                cv.u[0] = ua[0];   // k offsets {0,1}
                cv.u[1] = ub[0];   // k offsets {2,3}
                cv.u[2] = ua[1];   // k offsets {4,5}
                cv.u[3] = ub[1];   // k offsets {6,7}
                pf[sm][kc] = cv.s;
            }
        }

        // PV + l accumulation (l = P @ ones via MFMA)
        __builtin_amdgcn_s_setprio(1);
#pragma unroll
        for (int kc = 0; kc < 2; ++kc) {
            lacc[0] = __builtin_amdgcn_mfma_f32_16x16x32_bf16(pf[0][kc], vone, lacc[0], 0, 0, 0);
            lacc[1] = __builtin_amdgcn_mfma_f32_16x16x32_bf16(pf[1][kc], vone, lacc[1], 0, 0, 0);
#pragma unroll
            for (int dj = 0; dj < 4; ++dj) {
                const int row = dj * 16 + ln;
                const int cg  = (kc * 4 + quad) ^ (row & 7);
                const short8 vf = *(const short8*)&Vt[p][hf][row * 64 + cg * 8];
                O[0][dj] = __builtin_amdgcn_mfma_f32_16x16x32_bf16(pf[0][kc], vf, O[0][dj], 0, 0, 0);
                O[1][dj] = __builtin_amdgcn_mfma_f32_16x16x32_bf16(pf[1][kc], vf, O[1][dj], 0, 0, 0);
            }
        }
        __builtin_amdgcn_s_setprio(0);
        __syncthreads();
    }

    // ---- combine the two KV-halves: O = O_a + O_b, l = l_a + l_b ----
    float* Of = (float*)&Ks[0][0][0];   // 128 rows x 64 cols f32
    float* Lf = (float*)&Vt[0][0][0];   // 128 f32
    if (hf == 0) {
#pragma unroll
        for (int sm = 0; sm < 2; ++sm) {
#pragma unroll
            for (int dj = 0; dj < 4; ++dj)
#pragma unroll
                for (int r2 = 0; r2 < 4; ++r2)
                    Of[(w4 * 32 + sm * 16 + quad * 4 + r2) * 64 + dj * 16 + ln] =
                        O[sm][dj][r2];
            if (ln == 0)
#pragma unroll
                for (int r2 = 0; r2 < 4; ++r2)
                    Lf[w4 * 32 + sm * 16 + quad * 4 + r2] = lacc[sm][r2];
        }
    }
    __syncthreads();
    if (hf == 1) {
#pragma unroll
        for (int sm = 0; sm < 2; ++sm)
#pragma unroll
            for (int r2 = 0; r2 < 4; ++r2) {
                const int rr = w4 * 32 + sm * 16 + quad * 4 + r2;
                const float inv = 1.0f / (lacc[sm][r2] + Lf[rr]);
                const int row = b * SEQ + q0 + rr;
#pragma unroll
                for (int dj = 0; dj < 4; ++dj) {
                    const float val = O[sm][dj][r2] + Of[rr * 64 + dj * 16 + ln];
                    ctxbf[(size_t)row * DIM + h * HD + dj * 16 + ln] =
                        (unsigned short)f2bf(val * inv);
                }
            }
    }
}

// ======================================================================
// Out-proj GEMM: 3-buffer counted-vmcnt DMA pipeline.
// ======================================================================
__global__ __launch_bounds__(256)
void gemm_out(const unsigned short* __restrict__ A, const unsigned short* __restrict__ B,
              const float* __restrict__ bias, float* __restrict__ C)
{
    constexpr int BK = 32, NIT = DIM / BK;
    const int K = DIM, N = DIM;
    __shared__ short As[3][128 * BK];   // 3 x 8 KB
    __shared__ short Bs[3][64 * BK];    // 3 x 4 KB

    const int tid  = threadIdx.x;
    const int lane = tid & 63;
    const int wave = tid >> 6;
    const int quad = lane >> 4;
    const int ln   = lane & 15;
    const int wm   = (wave & 1) * 64;
    const int wn   = (wave >> 1) * 32;

    const int bid = blockIdx.x;
    const int xcd = bid & 7;
    const int t   = bid >> 3;
    const int m0  = (xcd * 4 + (t & 3)) * 128;
    const int n0  = (t >> 2) * 64;

    int srow[2], sg[2];
#pragma unroll
    for (int i = 0; i < 2; ++i) {
        const int c  = wave * 128 + i * 64 + lane;
        srow[i] = c >> 2;
        sg[i]   = (c & 3) ^ ((srow[i] >> 1) & 3);
    }
    const int cB  = wave * 64 + lane;
    const int brow = cB >> 2;
    const int bg   = (cB & 3) ^ ((brow >> 1) & 3);

    f32x4 acc[4][2];
#pragma unroll
    for (int i = 0; i < 4; ++i)
#pragma unroll
        for (int j = 0; j < 2; ++j) acc[i][j] = (f32x4){0.f, 0.f, 0.f, 0.f};

    // prologue: issue tiles 0 and 1 (6 ops outstanding)
#pragma unroll
    for (int t0 = 0; t0 < 2; ++t0) {
        const int kn = t0 * BK;
#pragma unroll
        for (int i = 0; i < 2; ++i)
            g2l16(A + (size_t)(m0 + srow[i]) * K + kn + sg[i] * 8,
                  &As[t0][(wave * 128 + i * 64) * 8]);
        g2l16(B + (size_t)(n0 + brow) * K + kn + bg * 8, &Bs[t0][(wave * 64) * 8]);
    }

    int bufc = 0;
    int bufn = 2;
    for (int kt = 0; kt < NIT; ++kt) {
        if (kt < NIT - 1) asm volatile("s_waitcnt vmcnt(3)" ::: "memory");
        else              asm volatile("s_waitcnt vmcnt(0)" ::: "memory");
        __builtin_amdgcn_s_barrier();
        __builtin_amdgcn_sched_barrier(0);

        short8 a[4], b[2];
#pragma unroll
        for (int i = 0; i < 4; ++i) {
            const int row = wm + i * 16 + ln;
            const int ch  = quad ^ ((row >> 1) & 3);
            a[i] = *(const short8*)&As[bufc][row * BK + ch * 8];
        }
#pragma unroll
        for (int j = 0; j < 2; ++j) {
            const int row = wn + j * 16 + ln;
            const int ch  = quad ^ ((row >> 1) & 3);
            b[j] = *(const short8*)&Bs[bufc][row * BK + ch * 8];
        }
        asm volatile("s_waitcnt lgkmcnt(0)" ::: "memory");
        __builtin_amdgcn_sched_barrier(0);

        if (kt + 2 < NIT) {
            const int kn = (kt + 2) * BK;
#pragma unroll
            for (int i = 0; i < 2; ++i)
                g2l16(A + (size_t)(m0 + srow[i]) * K + kn + sg[i] * 8,
                      &As[bufn][(wave * 128 + i * 64) * 8]);
            g2l16(B + (size_t)(n0 + brow) * K + kn + bg * 8, &Bs[bufn][(wave * 64) * 8]);
        }

#pragma unroll
        for (int i = 0; i < 4; ++i)
#pragma unroll
            for (int j = 0; j < 2; ++j)
                acc[i][j] = __builtin_amdgcn_mfma_f32_16x16x32_bf16(
                    a[i], b[j], acc[i][j], 0, 0, 0);

        bufc = (bufc == 2) ? 0 : bufc + 1;
        bufn = (bufn == 2) ? 0 : bufn + 1;
    }

#pragma unroll
    for (int j = 0; j < 2; ++j) {
        const int col = n0 + wn + j * 16 + ln;
        const float bv = bias[col];
#pragma unroll
        for (int i = 0; i < 4; ++i)
#pragma unroll
            for (int r2 = 0; r2 < 4; ++r2) {
                const int row = m0 + wm + i * 16 + quad * 4 + r2;
                C[(size_t)row * N + col] = acc[i][j][r2] + bv;
            }
    }
}

extern "C" void kernel_launch(void* const* d_in, const int* in_sizes, int n_in,
                              void* d_out, int out_size, void* d_ws, size_t ws_size,
                              hipStream_t stream)
{
    const float* x     = (const float*)d_in[0];
    const float* W_kqv = (const float*)d_in[1];
    const float* b_kqv = (const float*)d_in[2];
    const float* W_out = (const float*)d_in[3];
    const float* b_out = (const float*)d_in[4];
    float* out = (float*)d_out;

    char* w = (char*)d_ws;
    unsigned short* qbf   = (unsigned short*)w;  w += (size_t)BATCH * NHEAD * SEQ * HD * 2;
    unsigned short* kbf   = (unsigned short*)w;  w += (size_t)BATCH * NHEAD * SEQ * HD * 2;
    unsigned short* vtbf  = (unsigned short*)w;  w += (size_t)BATCH * NHEAD * HD * SEQ * 2;
    unsigned short* ctxbf = (unsigned short*)w;  w += (size_t)BATCH * SEQ * DIM * 2;
    unsigned short* xb    = (unsigned short*)w;  w += (size_t)BATCH * SEQ * DIM * 2;
    unsigned short* wkb   = (unsigned short*)w;  w += (size_t)QKV3 * DIM * 2;
    unsigned short* wob   = (unsigned short*)w;

    dim3 blk(256);

    conv_bf16<<<dim3(2048), blk, 0, stream>>>(x, W_kqv, W_out, xb, wkb, wob);

    gemm_qkv<<<dim3(768), blk, 0, stream>>>(xb, wkb, b_kqv, qbf, kbf, vtbf);

    attn_flash_mfma<<<dim3(512), dim3(512), 0, stream>>>(qbf, kbf, vtbf, ctxbf);

    gemm_out<<<dim3(512), blk, 0, stream>>>(ctxbf, wob, b_out, out);
}